// Round 13
// baseline (359.531 us; speedup 1.0000x reference)
//
#include <hip/hip_runtime.h>

#define N_NODES 50000
#define N_EDGES 800000
#define D 128
#define N_LAYERS 3
#define OUT_F 16
#define N_GRAPHS 128
#define NBUCK 391            // ceil(50000/128) buckets of 128 nodes
#define EPB 4096             // edges per partition block
#define NB3 ((N_EDGES + EPB - 1) / EPB)  // 196
#define CAP 4096             // padded bucket capacity (mean 2048, sigma ~45)
#define NT32 ((N_NODES + 31) / 32)       // 1563 row-tiles of 32
#define NSTRIP 4                         // 32-col strips: 3.2 MB table/strip
#define NCHUNK ((N_NODES + 63) / 64)     // 782 node-chunks of 64

typedef __attribute__((ext_vector_type(8))) short short8;
typedef __attribute__((ext_vector_type(16))) float floatx16;

__device__ __forceinline__ unsigned short f2bf(float f) {
  unsigned int u = __float_as_uint(f);
  u += 0x7fff + ((u >> 16) & 1);   // RNE
  return (unsigned short)(u >> 16);
}
__device__ __forceinline__ float bf2f(unsigned short b) {
  return __uint_as_float(((unsigned int)b) << 16);
}
__device__ __forceinline__ float blo(unsigned v) { return __uint_as_float(v << 16); }
__device__ __forceinline__ float bhi(unsigned v) { return __uint_as_float(v & 0xffff0000u); }

// ========== CSR build: padded-bucket counting sort (2 kernels) ==============
__global__ __launch_bounds__(256) void partition_kernel(
    const int* __restrict__ src, const int* __restrict__ dst,
    int* __restrict__ cursor, unsigned* __restrict__ pairs) {
  __shared__ unsigned pk[EPB];
  __shared__ int hist[NBUCK];
  __shared__ int wcur[NBUCK];
  const int e0 = blockIdx.x * EPB;
  const int n = min(EPB, N_EDGES - e0);
  const int t = threadIdx.x;
  for (int i = t; i < NBUCK; i += 256) hist[i] = 0;
  __syncthreads();
  for (int i = t; i < n; i += 256) {
    int d = dst[e0 + i], s = src[e0 + i];
    pk[i] = ((unsigned)d << 16) | (unsigned)s;
    atomicAdd(&hist[d >> 7], 1);
  }
  __syncthreads();
  for (int i = t; i < NBUCK; i += 256)
    wcur[i] = i * CAP + (hist[i] ? atomicAdd(&cursor[i], hist[i]) : 0);
  __syncthreads();
  for (int i = t; i < n; i += 256) {
    unsigned p = pk[i];
    int pos = atomicAdd(&wcur[p >> 23], 1);
    pairs[pos] = p;
  }
}

__global__ __launch_bounds__(256) void bucket_sort_kernel(
    const unsigned* __restrict__ pairs, const int* __restrict__ cursor,
    int* __restrict__ rowbeg, int* __restrict__ rowend, int* __restrict__ esrc) {
  __shared__ unsigned pk[CAP];
  __shared__ int sorted[CAP];
  __shared__ int hist[128], off[128], cur[128];
  const int bkt = blockIdx.x;
  const int t = threadIdx.x;
  const int beg = bkt * CAP;
  const int cnt = cursor[bkt];
  if (t < 128) hist[t] = 0;
  __syncthreads();
  for (int i = t; i < cnt; i += 256) {
    unsigned p = pairs[beg + i];
    pk[i] = p;
    atomicAdd(&hist[(p >> 16) & 127], 1);
  }
  __syncthreads();
  if (t < 128) off[t] = hist[t];
  __syncthreads();
  for (int o = 1; o < 128; o <<= 1) {
    int x = (t < 128 && t >= o) ? off[t - o] : 0;
    __syncthreads();
    if (t < 128) off[t] += x;
    __syncthreads();
  }
  if (t < 128) {
    int node = bkt * 128 + t;
    if (node < N_NODES) {
      rowbeg[node] = beg + off[t] - hist[t];
      rowend[node] = beg + off[t];
    }
    cur[t] = off[t] - hist[t];
  }
  __syncthreads();
  for (int i = t; i < cnt; i += 256) {
    unsigned p = pk[i];
    int pos = atomicAdd(&cur[(p >> 16) & 127], 1);
    sorted[pos] = (int)(p & 0xFFFFu);
  }
  __syncthreads();
  for (int i = t; i < cnt; i += 256) esrc[beg + i] = sorted[i];
}

// ========== merged prep: cast x -> bf16 AND weights -> MFMA-frag layout =====
// wt layout: [l][half:2][nt:2][kst:32][lane:64][j:8] bf16 (1 KB per frag).
__global__ __launch_bounds__(256) void prep_kernel(
    const float* __restrict__ x, unsigned short* __restrict__ x16,
    const float* __restrict__ Wrel, const float* __restrict__ Wroot,
    unsigned short* __restrict__ wt) {
  const int idx = blockIdx.x * 256 + threadIdx.x;
  if ((size_t)idx * 4 < (size_t)N_NODES * D) {
    const float4 v = *(const float4*)&x[(size_t)idx * 4];
    uint2 o;
    o.x = f2bf(v.x) | ((unsigned)f2bf(v.y) << 16);
    o.y = f2bf(v.z) | ((unsigned)f2bf(v.w) << 16);
    *(uint2*)&x16[(size_t)idx * 4] = o;
  }
  if (idx < N_LAYERS * 2 * 2 * 32 * 64) {
    const int lane = idx & 63;
    const int kst = (idx >> 6) & 31;
    const int nt = (idx >> 11) & 1;
    const int half = (idx >> 12) & 1;
    const int l = idx >> 13;
    const int n = half * 64 + nt * 32 + (lane & 31);
    const int kx0 = kst * 16 + (lane >> 5) * 8;
    const int seg = kx0 >> 7;           // same seg for all 8 j
    const int k0 = kx0 & 127;
    const int mat = seg >> 1, lo = seg & 1;
    const float* W = (mat ? Wroot : Wrel) + (size_t)l * D * D;
    unsigned short v[8];
#pragma unroll
    for (int j = 0; j < 8; ++j) {
      float w = W[(size_t)(k0 + j) * D + n];
      unsigned short hi = f2bf(w);
      v[j] = lo ? f2bf(w - bf2f(hi)) : hi;
    }
    unsigned short* dstp =
        wt + ((size_t)l * 128 + (half * 2 + nt) * 32 + kst) * 512 + lane * 8;
    *(uint4*)dstp = *(const uint4*)v;
  }
}

// ===== aggregate, column-strip version: strip working set 3.2 MB < L2 =======
// 4 lanes/node x 16B = one 32-col strip; strip is the SLOW grid index so
// dispatch order keeps ~1 strip active device-wide -> L2-resident gathers.
// Per-column edge order identical to the full-width version (bit-exact).
__global__ __launch_bounds__(256) void agg_kernel(
    const unsigned short* __restrict__ h,
    const int* __restrict__ rowbeg, const int* __restrict__ rowend,
    const int* __restrict__ esrc, unsigned short* __restrict__ agg) {
  const int strip = blockIdx.x / NCHUNK;
  const int chunk = blockIdx.x - strip * NCHUNK;
  const int t = threadIdx.x;
  const int n = chunk * 64 + (t >> 2);
  const int colb = strip * 32 + (t & 3) * 8;
  if (n >= N_NODES) return;
  const int beg = rowbeg[n], end = rowend[n];
  float a0 = 0, a1 = 0, a2 = 0, a3 = 0, a4 = 0, a5 = 0, a6 = 0, a7 = 0;
  int e = beg;
  for (; e + 8 <= end; e += 8) {
    uint4 v[8];
#pragma unroll
    for (int j = 0; j < 8; ++j) {
      const int s = esrc[e + j];
      v[j] = *(const uint4*)&h[(size_t)s * D + colb];
    }
#pragma unroll
    for (int j = 0; j < 8; ++j) {
      a0 += blo(v[j].x); a1 += bhi(v[j].x);
      a2 += blo(v[j].y); a3 += bhi(v[j].y);
      a4 += blo(v[j].z); a5 += bhi(v[j].z);
      a6 += blo(v[j].w); a7 += bhi(v[j].w);
    }
  }
  if (e + 4 <= end) {
    uint4 v[4];
#pragma unroll
    for (int j = 0; j < 4; ++j) {
      const int s = esrc[e + j];
      v[j] = *(const uint4*)&h[(size_t)s * D + colb];
    }
#pragma unroll
    for (int j = 0; j < 4; ++j) {
      a0 += blo(v[j].x); a1 += bhi(v[j].x);
      a2 += blo(v[j].y); a3 += bhi(v[j].y);
      a4 += blo(v[j].z); a5 += bhi(v[j].z);
      a6 += blo(v[j].w); a7 += bhi(v[j].w);
    }
    e += 4;
  }
  for (; e < end; ++e) {
    const int s0 = esrc[e];
    const uint4 v0 = *(const uint4*)&h[(size_t)s0 * D + colb];
    a0 += blo(v0.x); a1 += bhi(v0.x);
    a2 += blo(v0.y); a3 += bhi(v0.y);
    a4 += blo(v0.z); a5 += bhi(v0.z);
    a6 += blo(v0.w); a7 += bhi(v0.w);
  }
  uint4 o;
  o.x = f2bf(a0) | ((unsigned)f2bf(a1) << 16);
  o.y = f2bf(a2) | ((unsigned)f2bf(a3) << 16);
  o.z = f2bf(a4) | ((unsigned)f2bf(a5) << 16);
  o.w = f2bf(a6) | ((unsigned)f2bf(a7) << 16);
  *(uint4*)&agg[(size_t)n * D + colb] = o;
}

// ====== MFMA 32x32x16 GEMM, B staged in LDS (frag-order, conflict-free) =====
// grid = (256, 2); blockIdx.y = col half. 4 waves/block; grid-stride tiles.
__global__ __launch_bounds__(256, 2) void gemm32_kernel(
    const unsigned short* __restrict__ agg, const unsigned short* __restrict__ hv,
    const unsigned short* __restrict__ wt, const float* __restrict__ brel,
    unsigned short* __restrict__ outp) {
  __shared__ unsigned short blds[32768];   // 64 KB: this half's 64 frag-sets
  const int t = threadIdx.x;
  const int wave = t >> 6, lane = t & 63;
  const int half = blockIdx.y;

  {
    const unsigned short* wsrc = wt + (size_t)half * 32768;
#pragma unroll
    for (int i = 0; i < 16; ++i) {
      const int idx = t + i * 256;   // 0..4095 uint4 units
      *(uint4*)&blds[idx * 8] = *(const uint4*)&wsrc[idx * 8];
    }
  }
  __syncthreads();

  const int r_lane = lane & 31;
  const int hseg = lane >> 5;
  const float bias0 = brel[half * 64 + r_lane];
  const float bias1 = brel[half * 64 + 32 + r_lane];

  const int nwaves = gridDim.x * 4;
  for (int tile = blockIdx.x * 4 + wave; tile < NT32; tile += nwaves) {
    const int r0 = tile * 32;
    int arow = r0 + r_lane;
    if (arow >= N_NODES) arow = N_NODES - 1;
    const unsigned short* ap = agg + (size_t)arow * D + hseg * 8;
    const unsigned short* hp = hv + (size_t)arow * D + hseg * 8;
    short8 ag[8], hh[8];
#pragma unroll
    for (int i = 0; i < 8; ++i) {
      ag[i] = *(const short8*)(ap + i * 16);
      hh[i] = *(const short8*)(hp + i * 16);
    }
    floatx16 acc0 = {0.f}, acc1 = {0.f};
#pragma unroll
    for (int kst = 0; kst < 32; ++kst) {
      const short8 af = (kst < 16) ? ag[kst & 7] : hh[kst & 7];
      const short8 b0 = *(const short8*)&blds[(size_t)kst * 512 + lane * 8];
      const short8 b1 = *(const short8*)&blds[(size_t)(32 + kst) * 512 + lane * 8];
      acc0 = __builtin_amdgcn_mfma_f32_32x32x16_bf16(af, b0, acc0, 0, 0, 0);
      acc1 = __builtin_amdgcn_mfma_f32_32x32x16_bf16(af, b1, acc1, 0, 0, 0);
    }
    const int cb = half * 64 + r_lane;
#pragma unroll
    for (int reg = 0; reg < 16; ++reg) {
      const int row = r0 + (reg & 3) + 8 * (reg >> 2) + 4 * hseg;
      if (row < N_NODES) {
        outp[(size_t)row * D + cb] = f2bf(fmaxf(acc0[reg] + bias0, 0.f));
        outp[(size_t)row * D + cb + 32] = f2bf(fmaxf(acc1[reg] + bias1, 0.f));
      }
    }
  }
}

// ============= pool (segment ranges; batch sorted) + MLP head ===============
__device__ __forceinline__ int lb_search(const int* __restrict__ a, int n, int key) {
  int lo = 0, hi = n;
  while (lo < hi) {
    int m = (lo + hi) >> 1;
    if (a[m] < key) lo = m + 1; else hi = m;
  }
  return lo;
}

__global__ __launch_bounds__(256) void pool_head_kernel(
    const unsigned short* __restrict__ h, const int* __restrict__ batch,
    const float* __restrict__ W1, const float* __restrict__ b1,
    const float* __restrict__ W2, const float* __restrict__ b2,
    float* __restrict__ out) {
  __shared__ float sums_lds[16][128];
  __shared__ float pooled[128];
  __shared__ float hidden[128];
  __shared__ int range[2];
  const int g = blockIdx.x;
  const int t = threadIdx.x;
  if (t < 2) range[t] = lb_search(batch, N_NODES, g + t);
  __syncthreads();
  const int lo = range[0], hi = range[1];
  const int rg = t >> 4, cg = t & 15;
  float a0 = 0, a1 = 0, a2 = 0, a3 = 0, a4 = 0, a5 = 0, a6 = 0, a7 = 0;
  for (int n = lo + rg; n < hi; n += 16) {
    const uint4 v = *(const uint4*)&h[(size_t)n * D + cg * 8];
    a0 += blo(v.x); a1 += bhi(v.x);
    a2 += blo(v.y); a3 += bhi(v.y);
    a4 += blo(v.z); a5 += bhi(v.z);
    a6 += blo(v.w); a7 += bhi(v.w);
  }
  sums_lds[rg][cg * 8 + 0] = a0; sums_lds[rg][cg * 8 + 1] = a1;
  sums_lds[rg][cg * 8 + 2] = a2; sums_lds[rg][cg * 8 + 3] = a3;
  sums_lds[rg][cg * 8 + 4] = a4; sums_lds[rg][cg * 8 + 5] = a5;
  sums_lds[rg][cg * 8 + 6] = a6; sums_lds[rg][cg * 8 + 7] = a7;
  __syncthreads();
  if (t < 128) {
    float s = 0.f;
#pragma unroll
    for (int r = 0; r < 16; ++r) s += sums_lds[r][t];
    pooled[t] = s / fmaxf((float)(hi - lo), 1.f);
  }
  __syncthreads();
  if (t < 128) {
    float a = b1[t];
    for (int k = 0; k < D; ++k) a += pooled[k] * W1[k * D + t];
    hidden[t] = a;
  }
  __syncthreads();
  if (t < OUT_F) {
    float o = b2[t];
    for (int k = 0; k < D; ++k) o += hidden[k] * W2[k * OUT_F + t];
    out[(size_t)g * OUT_F + t] = o;
  }
}

// ============================== launch ======================================
extern "C" void kernel_launch(void* const* d_in, const int* in_sizes, int n_in,
                              void* d_out, int out_size, void* d_ws, size_t ws_size,
                              hipStream_t stream) {
  const float* x     = (const float*)d_in[0];
  const int*   ei    = (const int*)d_in[1];
  const int*   batch = (const int*)d_in[2];
  const float* Wrel  = (const float*)d_in[3];
  const float* brel  = (const float*)d_in[4];
  const float* Wroot = (const float*)d_in[5];
  const float* W1    = (const float*)d_in[6];
  const float* b1    = (const float*)d_in[7];
  const float* W2    = (const float*)d_in[8];
  const float* b2    = (const float*)d_in[9];
  float* out = (float*)d_out;

  const size_t ND = (size_t)N_NODES * D;
  unsigned short* bufA = (unsigned short*)d_ws;            // N*D bf16
  unsigned short* bufB = bufA + ND;                        // N*D bf16
  unsigned short* bufC = bufB + ND;                        // N*D bf16 (x16)
  unsigned short* wt   = bufC + ND;                        // 3*128*512 bf16
  int* rowbeg = (int*)(wt + (size_t)N_LAYERS * 128 * 512); // N
  int* rowend = rowbeg + N_NODES;                          // N
  int* esrc   = rowend + N_NODES;                          // NBUCK*CAP
  unsigned* pairs = (unsigned*)(esrc + (size_t)NBUCK * CAP);  // NBUCK*CAP
  int* cursor = (int*)(pairs + (size_t)NBUCK * CAP);       // NBUCK

  const int* esrc_in = ei;
  const int* edst_in = ei + N_EDGES;

  // ---- CSR build (padded buckets, 2 kernels) ----
  hipMemsetAsync(cursor, 0, NBUCK * sizeof(int), stream);
  partition_kernel<<<NB3, 256, 0, stream>>>(esrc_in, edst_in, cursor, pairs);
  bucket_sort_kernel<<<NBUCK, 256, 0, stream>>>(pairs, cursor, rowbeg, rowend, esrc);

  // ---- merged prep (x cast + weight frag packing) ----
  prep_kernel<<<(int)((ND / 4 + 255) / 256), 256, 0, stream>>>(
      x, bufC, Wrel, Wroot, wt);

  // ---- 3 layers (strip-agg + gemm, out-of-place rotation) ----
  const dim3 ggrid(256, 2);
  const int agg_blocks = NSTRIP * NCHUNK;   // 3128
  const size_t WL = (size_t)128 * 512;
  // l0: agg(x16=bufC)->bufA ; gemm(bufA,bufC)->bufB
  agg_kernel<<<agg_blocks, 256, 0, stream>>>(bufC, rowbeg, rowend, esrc, bufA);
  gemm32_kernel<<<ggrid, 256, 0, stream>>>(bufA, bufC, wt, brel, bufB);
  // l1: agg(bufB)->bufA ; gemm(bufA,bufB)->bufC
  agg_kernel<<<agg_blocks, 256, 0, stream>>>(bufB, rowbeg, rowend, esrc, bufA);
  gemm32_kernel<<<ggrid, 256, 0, stream>>>(bufA, bufB, wt + WL, brel + D, bufC);
  // l2: agg(bufC)->bufB ; gemm(bufB,bufC)->bufA
  agg_kernel<<<agg_blocks, 256, 0, stream>>>(bufC, rowbeg, rowend, esrc, bufB);
  gemm32_kernel<<<ggrid, 256, 0, stream>>>(bufB, bufC, wt + 2 * WL, brel + 2 * D, bufA);

  pool_head_kernel<<<N_GRAPHS, 256, 0, stream>>>(bufA, batch, W1, b1, W2, b2, out);
}

// Round 14
// 315.586 us; speedup vs baseline: 1.1392x; 1.1392x over previous
//
#include <hip/hip_runtime.h>

#define N_NODES 50000
#define N_EDGES 800000
#define D 128
#define N_LAYERS 3
#define OUT_F 16
#define N_GRAPHS 128
#define NBUCK 391            // ceil(50000/128) buckets of 128 nodes
#define EPB 4096             // edges per partition block
#define NB3 ((N_EDGES + EPB - 1) / EPB)  // 196
#define CAP 4096             // padded bucket capacity (mean 2048, sigma ~45)
#define NT32 ((N_NODES + 31) / 32)       // 1563 row-tiles of 32

typedef __attribute__((ext_vector_type(8))) short short8;
typedef __attribute__((ext_vector_type(16))) float floatx16;

__device__ __forceinline__ unsigned short f2bf(float f) {
  unsigned int u = __float_as_uint(f);
  u += 0x7fff + ((u >> 16) & 1);   // RNE
  return (unsigned short)(u >> 16);
}
__device__ __forceinline__ float bf2f(unsigned short b) {
  return __uint_as_float(((unsigned int)b) << 16);
}
__device__ __forceinline__ float blo(unsigned v) { return __uint_as_float(v << 16); }
__device__ __forceinline__ float bhi(unsigned v) { return __uint_as_float(v & 0xffff0000u); }

// ========== CSR build: padded-bucket counting sort (2 kernels) ==============
__global__ __launch_bounds__(256) void partition_kernel(
    const int* __restrict__ src, const int* __restrict__ dst,
    int* __restrict__ cursor, unsigned* __restrict__ pairs) {
  __shared__ unsigned pk[EPB];
  __shared__ int hist[NBUCK];
  __shared__ int wcur[NBUCK];
  const int e0 = blockIdx.x * EPB;
  const int n = min(EPB, N_EDGES - e0);
  const int t = threadIdx.x;
  for (int i = t; i < NBUCK; i += 256) hist[i] = 0;
  __syncthreads();
  for (int i = t; i < n; i += 256) {
    int d = dst[e0 + i], s = src[e0 + i];
    pk[i] = ((unsigned)d << 16) | (unsigned)s;
    atomicAdd(&hist[d >> 7], 1);
  }
  __syncthreads();
  for (int i = t; i < NBUCK; i += 256)
    wcur[i] = i * CAP + (hist[i] ? atomicAdd(&cursor[i], hist[i]) : 0);
  __syncthreads();
  for (int i = t; i < n; i += 256) {
    unsigned p = pk[i];
    int pos = atomicAdd(&wcur[p >> 23], 1);
    pairs[pos] = p;
  }
}

__global__ __launch_bounds__(256) void bucket_sort_kernel(
    const unsigned* __restrict__ pairs, const int* __restrict__ cursor,
    int* __restrict__ rowbeg, int* __restrict__ rowend, int* __restrict__ esrc) {
  __shared__ unsigned pk[CAP];
  __shared__ int sorted[CAP];
  __shared__ int hist[128], off[128], cur[128];
  const int bkt = blockIdx.x;
  const int t = threadIdx.x;
  const int beg = bkt * CAP;
  const int cnt = cursor[bkt];
  if (t < 128) hist[t] = 0;
  __syncthreads();
  for (int i = t; i < cnt; i += 256) {
    unsigned p = pairs[beg + i];
    pk[i] = p;
    atomicAdd(&hist[(p >> 16) & 127], 1);
  }
  __syncthreads();
  if (t < 128) off[t] = hist[t];
  __syncthreads();
  for (int o = 1; o < 128; o <<= 1) {
    int x = (t < 128 && t >= o) ? off[t - o] : 0;
    __syncthreads();
    if (t < 128) off[t] += x;
    __syncthreads();
  }
  if (t < 128) {
    int node = bkt * 128 + t;
    if (node < N_NODES) {
      rowbeg[node] = beg + off[t] - hist[t];
      rowend[node] = beg + off[t];
    }
    cur[t] = off[t] - hist[t];
  }
  __syncthreads();
  for (int i = t; i < cnt; i += 256) {
    unsigned p = pk[i];
    int pos = atomicAdd(&cur[(p >> 16) & 127], 1);
    sorted[pos] = (int)(p & 0xFFFFu);
  }
  __syncthreads();
  for (int i = t; i < cnt; i += 256) esrc[beg + i] = sorted[i];
}

// ================= prep: cast x -> bf16; weights -> MFMA-frag layout ========
__global__ __launch_bounds__(256) void cast_x_kernel(
    const float* __restrict__ x, unsigned short* __restrict__ x16) {
  int i = blockIdx.x * 256 + threadIdx.x;          // handles 4 floats
  if ((size_t)i * 4 >= (size_t)N_NODES * D) return;
  const float4 v = *(const float4*)&x[(size_t)i * 4];
  uint2 o;
  o.x = f2bf(v.x) | ((unsigned)f2bf(v.y) << 16);
  o.y = f2bf(v.z) | ((unsigned)f2bf(v.w) << 16);
  *(uint2*)&x16[(size_t)i * 4] = o;
}

// wt layout: [l][half:2][nt:2][kst:32][lane:64][j:8] bf16 (1 KB per frag).
// Element (lane,j) = B[kx][n], n = half*64+nt*32+(lane&31),
// kx = kst*16+(lane>>5)*8+j; kx = seg*128+k, segs {rel_hi,rel_lo,root_hi,root_lo}.
__global__ __launch_bounds__(256) void prep_w_kernel(
    const float* __restrict__ Wrel, const float* __restrict__ Wroot,
    unsigned short* __restrict__ wt) {
  int idx = blockIdx.x * 256 + threadIdx.x;   // 3*2*2*32*64 = 24576 threads
  if (idx >= N_LAYERS * 2 * 2 * 32 * 64) return;
  const int lane = idx & 63;
  const int kst = (idx >> 6) & 31;
  const int nt = (idx >> 11) & 1;
  const int half = (idx >> 12) & 1;
  const int l = idx >> 13;
  const int n = half * 64 + nt * 32 + (lane & 31);
  const int kx0 = kst * 16 + (lane >> 5) * 8;
  const int seg = kx0 >> 7;           // same seg for all 8 j
  const int k0 = kx0 & 127;
  const int mat = seg >> 1, lo = seg & 1;
  const float* W = (mat ? Wroot : Wrel) + (size_t)l * D * D;
  unsigned short v[8];
#pragma unroll
  for (int j = 0; j < 8; ++j) {
    float w = W[(size_t)(k0 + j) * D + n];
    unsigned short hi = f2bf(w);
    v[j] = lo ? f2bf(w - bf2f(hi)) : hi;
  }
  unsigned short* dstp =
      wt + ((size_t)l * 128 + (half * 2 + nt) * 32 + kst) * 512 + lane * 8;
  *(uint4*)dstp = *(const uint4*)v;
}

// ===== aggregate: 16 lanes/node (4 nodes/wave), uint4 loads, 4-edge unroll ==
__global__ __launch_bounds__(256) void agg_kernel(
    const unsigned short* __restrict__ h,
    const int* __restrict__ rowbeg, const int* __restrict__ rowend,
    const int* __restrict__ esrc, unsigned short* __restrict__ agg) {
  const int idx = blockIdx.x * 256 + threadIdx.x;
  const int n = idx >> 4;
  const int lane = idx & 15;
  if (n >= N_NODES) return;
  const int beg = rowbeg[n], end = rowend[n];
  float a0 = 0, a1 = 0, a2 = 0, a3 = 0, a4 = 0, a5 = 0, a6 = 0, a7 = 0;
  int e = beg;
  for (; e + 4 <= end; e += 4) {
    const int s0 = esrc[e],     s1 = esrc[e + 1];
    const int s2 = esrc[e + 2], s3 = esrc[e + 3];
    const uint4 v0 = *(const uint4*)&h[(size_t)s0 * D + lane * 8];
    const uint4 v1 = *(const uint4*)&h[(size_t)s1 * D + lane * 8];
    const uint4 v2 = *(const uint4*)&h[(size_t)s2 * D + lane * 8];
    const uint4 v3 = *(const uint4*)&h[(size_t)s3 * D + lane * 8];
    a0 += blo(v0.x) + blo(v1.x) + blo(v2.x) + blo(v3.x);
    a1 += bhi(v0.x) + bhi(v1.x) + bhi(v2.x) + bhi(v3.x);
    a2 += blo(v0.y) + blo(v1.y) + blo(v2.y) + blo(v3.y);
    a3 += bhi(v0.y) + bhi(v1.y) + bhi(v2.y) + bhi(v3.y);
    a4 += blo(v0.z) + blo(v1.z) + blo(v2.z) + blo(v3.z);
    a5 += bhi(v0.z) + bhi(v1.z) + bhi(v2.z) + bhi(v3.z);
    a6 += blo(v0.w) + blo(v1.w) + blo(v2.w) + blo(v3.w);
    a7 += bhi(v0.w) + bhi(v1.w) + bhi(v2.w) + bhi(v3.w);
  }
  for (; e < end; ++e) {
    const int s0 = esrc[e];
    const uint4 v0 = *(const uint4*)&h[(size_t)s0 * D + lane * 8];
    a0 += blo(v0.x); a1 += bhi(v0.x);
    a2 += blo(v0.y); a3 += bhi(v0.y);
    a4 += blo(v0.z); a5 += bhi(v0.z);
    a6 += blo(v0.w); a7 += bhi(v0.w);
  }
  uint4 o;
  o.x = f2bf(a0) | ((unsigned)f2bf(a1) << 16);
  o.y = f2bf(a2) | ((unsigned)f2bf(a3) << 16);
  o.z = f2bf(a4) | ((unsigned)f2bf(a5) << 16);
  o.w = f2bf(a6) | ((unsigned)f2bf(a7) << 16);
  *(uint4*)&agg[(size_t)n * D + lane * 8] = o;
}

// ====== MFMA 32x32x16 GEMM, B staged in LDS (frag-order, conflict-free) =====
// grid = (196, 2); blockIdx.y = col half. 4 waves/block; wave handles whole
// 32-row tiles (grid-stride), 64 cols (2 n-tiles of 32). Out-of-place.
__global__ __launch_bounds__(256, 2) void gemm32_kernel(
    const unsigned short* __restrict__ agg, const unsigned short* __restrict__ hv,
    const unsigned short* __restrict__ wt, const float* __restrict__ brel,
    unsigned short* __restrict__ outp) {
  __shared__ unsigned short blds[32768];   // 64 KB: this half's 64 frag-sets
  const int t = threadIdx.x;
  const int wave = t >> 6, lane = t & 63;
  const int half = blockIdx.y;

  // stage B: linear 64 KB copy (coalesced dwordx4)
  {
    const unsigned short* wsrc = wt + (size_t)half * 32768;
#pragma unroll
    for (int i = 0; i < 16; ++i) {
      const int idx = t + i * 256;   // 0..4095 uint4 units
      *(uint4*)&blds[idx * 8] = *(const uint4*)&wsrc[idx * 8];
    }
  }
  __syncthreads();

  const int r_lane = lane & 31;       // A row within tile / C col within ntile
  const int hseg = lane >> 5;         // 0/1
  const float bias0 = brel[half * 64 + r_lane];
  const float bias1 = brel[half * 64 + 32 + r_lane];

  const int nwaves = gridDim.x * 4;
  for (int tile = blockIdx.x * 4 + wave; tile < NT32; tile += nwaves) {
    const int r0 = tile * 32;
    int arow = r0 + r_lane;
    if (arow >= N_NODES) arow = N_NODES - 1;
    const unsigned short* ap = agg + (size_t)arow * D + hseg * 8;
    const unsigned short* hp = hv + (size_t)arow * D + hseg * 8;
    short8 ag[8], hh[8];
#pragma unroll
    for (int i = 0; i < 8; ++i) {
      ag[i] = *(const short8*)(ap + i * 16);
      hh[i] = *(const short8*)(hp + i * 16);
    }
    floatx16 acc0 = {0.f}, acc1 = {0.f};
#pragma unroll
    for (int kst = 0; kst < 32; ++kst) {
      const short8 af = (kst < 16) ? ag[kst & 7] : hh[kst & 7];
      const short8 b0 = *(const short8*)&blds[(size_t)kst * 512 + lane * 8];
      const short8 b1 = *(const short8*)&blds[(size_t)(32 + kst) * 512 + lane * 8];
      acc0 = __builtin_amdgcn_mfma_f32_32x32x16_bf16(af, b0, acc0, 0, 0, 0);
      acc1 = __builtin_amdgcn_mfma_f32_32x32x16_bf16(af, b1, acc1, 0, 0, 0);
    }
    // epilogue: col = half*64 + nt*32 + (lane&31); row = (reg&3)+8*(reg>>2)+4*hseg
    const int cb = half * 64 + r_lane;
#pragma unroll
    for (int reg = 0; reg < 16; ++reg) {
      const int row = r0 + (reg & 3) + 8 * (reg >> 2) + 4 * hseg;
      if (row < N_NODES) {
        outp[(size_t)row * D + cb] = f2bf(fmaxf(acc0[reg] + bias0, 0.f));
        outp[(size_t)row * D + cb + 32] = f2bf(fmaxf(acc1[reg] + bias1, 0.f));
      }
    }
  }
}

// ============= pool (segment ranges; batch sorted) + MLP head ===============
__device__ __forceinline__ int lb_search(const int* __restrict__ a, int n, int key) {
  int lo = 0, hi = n;
  while (lo < hi) {
    int m = (lo + hi) >> 1;
    if (a[m] < key) lo = m + 1; else hi = m;
  }
  return lo;
}

__global__ __launch_bounds__(256) void pool_head_kernel(
    const unsigned short* __restrict__ h, const int* __restrict__ batch,
    const float* __restrict__ W1, const float* __restrict__ b1,
    const float* __restrict__ W2, const float* __restrict__ b2,
    float* __restrict__ out) {
  __shared__ float sums_lds[16][128];
  __shared__ float pooled[128];
  __shared__ float hidden[128];
  __shared__ int range[2];
  const int g = blockIdx.x;
  const int t = threadIdx.x;
  if (t < 2) range[t] = lb_search(batch, N_NODES, g + t);
  __syncthreads();
  const int lo = range[0], hi = range[1];
  const int rg = t >> 4, cg = t & 15;
  float a0 = 0, a1 = 0, a2 = 0, a3 = 0, a4 = 0, a5 = 0, a6 = 0, a7 = 0;
  for (int n = lo + rg; n < hi; n += 16) {
    const uint4 v = *(const uint4*)&h[(size_t)n * D + cg * 8];
    a0 += blo(v.x); a1 += bhi(v.x);
    a2 += blo(v.y); a3 += bhi(v.y);
    a4 += blo(v.z); a5 += bhi(v.z);
    a6 += blo(v.w); a7 += bhi(v.w);
  }
  sums_lds[rg][cg * 8 + 0] = a0; sums_lds[rg][cg * 8 + 1] = a1;
  sums_lds[rg][cg * 8 + 2] = a2; sums_lds[rg][cg * 8 + 3] = a3;
  sums_lds[rg][cg * 8 + 4] = a4; sums_lds[rg][cg * 8 + 5] = a5;
  sums_lds[rg][cg * 8 + 6] = a6; sums_lds[rg][cg * 8 + 7] = a7;
  __syncthreads();
  if (t < 128) {
    float s = 0.f;
#pragma unroll
    for (int r = 0; r < 16; ++r) s += sums_lds[r][t];
    pooled[t] = s / fmaxf((float)(hi - lo), 1.f);
  }
  __syncthreads();
  if (t < 128) {
    float a = b1[t];
    for (int k = 0; k < D; ++k) a += pooled[k] * W1[k * D + t];
    hidden[t] = a;
  }
  __syncthreads();
  if (t < OUT_F) {
    float o = b2[t];
    for (int k = 0; k < D; ++k) o += hidden[k] * W2[k * OUT_F + t];
    out[(size_t)g * OUT_F + t] = o;
  }
}

// ============================== launch ======================================
extern "C" void kernel_launch(void* const* d_in, const int* in_sizes, int n_in,
                              void* d_out, int out_size, void* d_ws, size_t ws_size,
                              hipStream_t stream) {
  const float* x     = (const float*)d_in[0];
  const int*   ei    = (const int*)d_in[1];
  const int*   batch = (const int*)d_in[2];
  const float* Wrel  = (const float*)d_in[3];
  const float* brel  = (const float*)d_in[4];
  const float* Wroot = (const float*)d_in[5];
  const float* W1    = (const float*)d_in[6];
  const float* b1    = (const float*)d_in[7];
  const float* W2    = (const float*)d_in[8];
  const float* b2    = (const float*)d_in[9];
  float* out = (float*)d_out;

  const size_t ND = (size_t)N_NODES * D;
  unsigned short* bufA = (unsigned short*)d_ws;            // N*D bf16
  unsigned short* bufB = bufA + ND;                        // N*D bf16
  unsigned short* bufC = bufB + ND;                        // N*D bf16 (x16)
  unsigned short* wt   = bufC + ND;                        // 3*128*512 bf16
  int* rowbeg = (int*)(wt + (size_t)N_LAYERS * 128 * 512); // N
  int* rowend = rowbeg + N_NODES;                          // N
  int* esrc   = rowend + N_NODES;                          // NBUCK*CAP
  unsigned* pairs = (unsigned*)(esrc + (size_t)NBUCK * CAP);  // NBUCK*CAP
  int* cursor = (int*)(pairs + (size_t)NBUCK * CAP);       // NBUCK

  const int* esrc_in = ei;
  const int* edst_in = ei + N_EDGES;

  // ---- CSR build (padded buckets, 2 kernels) ----
  hipMemsetAsync(cursor, 0, NBUCK * sizeof(int), stream);
  partition_kernel<<<NB3, 256, 0, stream>>>(esrc_in, edst_in, cursor, pairs);
  bucket_sort_kernel<<<NBUCK, 256, 0, stream>>>(pairs, cursor, rowbeg, rowend, esrc);

  // ---- prep bf16 ----
  cast_x_kernel<<<(int)((ND / 4 + 255) / 256), 256, 0, stream>>>(x, bufC);
  prep_w_kernel<<<(N_LAYERS * 2 * 2 * 32 * 64 + 255) / 256, 256, 0, stream>>>(
      Wrel, Wroot, wt);

  // ---- 3 layers (agg + gemm, out-of-place rotation) ----
  const dim3 ggrid(196, 2);
  const int agg_blocks = (N_NODES * 16 + 255) / 256;   // 3125
  const size_t WL = (size_t)128 * 512;
  // l0: agg(x16=bufC)->bufA ; gemm(bufA,bufC)->bufB
  agg_kernel<<<agg_blocks, 256, 0, stream>>>(bufC, rowbeg, rowend, esrc, bufA);
  gemm32_kernel<<<ggrid, 256, 0, stream>>>(bufA, bufC, wt, brel, bufB);
  // l1: agg(bufB)->bufA ; gemm(bufA,bufB)->bufC
  agg_kernel<<<agg_blocks, 256, 0, stream>>>(bufB, rowbeg, rowend, esrc, bufA);
  gemm32_kernel<<<ggrid, 256, 0, stream>>>(bufA, bufB, wt + WL, brel + D, bufC);
  // l2: agg(bufC)->bufB ; gemm(bufB,bufC)->bufA
  agg_kernel<<<agg_blocks, 256, 0, stream>>>(bufC, rowbeg, rowend, esrc, bufB);
  gemm32_kernel<<<ggrid, 256, 0, stream>>>(bufB, bufC, wt + 2 * WL, brel + 2 * D, bufA);

  pool_head_kernel<<<N_GRAPHS, 256, 0, stream>>>(bufA, batch, W1, b1, W2, b2, out);
}